// Round 3
// baseline (167.005 us; speedup 1.0000x reference)
//
#include <hip/hip_runtime.h>
#include <cstdint>

#define B_ 32
#define P_ 65536
#define O_ 32
#define GX_ 64            // grid.x; each block handles KC_ chunks of 256 priors
#define KC_ 4             // (P_/256)/GX_
#define THRESH_ 0.35f
#define VAR0 0.1f
#define VAR1 0.2f
#define EPS_ 1e-7f
#define ALPHA_ 0.25f

struct WSHdr {
  unsigned long long gkey[B_ * O_];  // per (b,o): packed (iou_bits<<32)|(~p)
  float4 part[GX_ * B_];             // per-block partials (ll, lc, llm, n1)
};
// BIG layout: WSHdr followed by uint2 pb[B_*P_]  ({iou_bits, best_truth_idx})

__device__ __forceinline__ float frcp(float x) { return __builtin_amdgcn_rcpf(x); }

__global__ void init_ws(WSHdr* ws) {
  int t = blockIdx.x * blockDim.x + threadIdx.x;
  if (t < B_ * O_) ws->gkey[t] = 0ull;
}

// ------- kernel 1: IoU pass — per-truth argmax + (BIG) per-prior best -------
template <bool BIG>
__global__ __launch_bounds__(256) void k_match(const float* __restrict__ priors,
                                               const float* __restrict__ targets,
                                               WSHdr* __restrict__ ws,
                                               uint2* __restrict__ pb) {
  __shared__ unsigned long long lkey[O_];
  const int b = blockIdx.y;
  const int tid = threadIdx.x;
  if (tid < O_) lkey[tid] = 0xFFFFFFFFull;  // key(iou=0, p=0)
  __syncthreads();

  // this thread's KC_ priors, in registers
  float px1[KC_], py1[KC_], px2[KC_], py2[KC_], parea[KC_];
  float bov[KC_];
  int bidx[KC_];
  unsigned pidx[KC_];
  #pragma unroll
  for (int k = 0; k < KC_; ++k) {
    unsigned p = (unsigned)((blockIdx.x + k * GX_) * 256 + tid);
    pidx[k] = p;
    float4 pr = reinterpret_cast<const float4*>(priors)[p];
    px1[k] = pr.x - pr.z * 0.5f; py1[k] = pr.y - pr.w * 0.5f;
    px2[k] = pr.x + pr.z * 0.5f; py2[k] = pr.y + pr.w * 0.5f;
    parea[k] = (px2[k] - px1[k]) * (py2[k] - py1[k]);
    bov[k] = -1.f; bidx[k] = 0;
  }

  for (int o = 0; o < O_; ++o) {
    // uniform index -> scalar loads
    const float* trow = targets + ((size_t)b * O_ + o) * 15;
    const float x1 = trow[0], y1 = trow[1], x2 = trow[2], y2 = trow[3];
    const float ta = (x2 - x1) * (y2 - y1);
    float tiou = 0.f;
    unsigned tp = 0;
    #pragma unroll
    for (int k = 0; k < KC_; ++k) {
      float iw = fmaxf(fminf(x2, px2[k]) - fmaxf(x1, px1[k]), 0.f);
      float ih = fmaxf(fminf(y2, py2[k]) - fmaxf(y1, py1[k]), 0.f);
      float inter = iw * ih;
      float iou = inter * frcp(ta + parea[k] - inter);
      if (iou > bov[k]) { bov[k] = iou; bidx[k] = o; }   // first-occurrence (o asc)
      if (iou > tiou) { tiou = iou; tp = pidx[k]; }      // first-occurrence (p asc)
    }
    unsigned long long key = ((unsigned long long)__float_as_uint(tiou) << 32) |
                             (unsigned long long)(0xFFFFFFFFu - tp);
    if (key > lkey[o]) atomicMax(&lkey[o], key);
  }

  if (BIG) {
    #pragma unroll
    for (int k = 0; k < KC_; ++k)
      pb[(size_t)b * P_ + pidx[k]] = make_uint2(__float_as_uint(bov[k]), (unsigned)bidx[k]);
  }
  __syncthreads();
  if (tid < O_) atomicMax(&ws->gkey[(size_t)b * O_ + tid], lkey[tid]);
}

// ------- kernel 1b (BIG): apply forced matches, last-j-wins ------------------
__global__ void k_forced(const WSHdr* __restrict__ ws, uint2* __restrict__ pb) {
  int b = threadIdx.x;
  if (b >= B_) return;
  for (int j = 0; j < O_; ++j) {  // sequential in one thread => last j wins
    unsigned fp = 0xFFFFFFFFu - (unsigned)(ws->gkey[b * O_ + j] & 0xFFFFFFFFull);
    pb[(size_t)b * P_ + fp] = make_uint2(__float_as_uint(2.0f), (unsigned)j);
  }
}

// ------- kernel 2: losses ----------------------------------------------------
template <bool BIG>
__global__ __launch_bounds__(256) void k_loss(const float* __restrict__ loc_data,
                                              const float* __restrict__ conf_data,
                                              const float* __restrict__ landm_data,
                                              const float* __restrict__ priors,
                                              const float* __restrict__ targets,
                                              WSHdr* __restrict__ ws,
                                              const uint2* __restrict__ pb) {
  __shared__ float tx1[O_], ty1[O_], tx2[O_], ty2[O_], tarea[O_], tlbl[O_];
  __shared__ float tlm[O_][10];
  __shared__ unsigned int fprior[O_];
  __shared__ float4 wsum[4];
  const int b = blockIdx.y;
  const int tid = threadIdx.x;
  if (tid < O_) {
    const float* trow = targets + ((size_t)b * O_ + tid) * 15;
    float x1 = trow[0], y1 = trow[1], x2 = trow[2], y2 = trow[3];
    tx1[tid] = x1; ty1[tid] = y1; tx2[tid] = x2; ty2[tid] = y2;
    tarea[tid] = (x2 - x1) * (y2 - y1);
    #pragma unroll
    for (int k = 0; k < 10; ++k) tlm[tid][k] = trow[4 + k];
    tlbl[tid] = trow[14];
    if (!BIG)
      fprior[tid] = 0xFFFFFFFFu - (unsigned)(ws->gkey[(size_t)b * O_ + tid] & 0xFFFFFFFFull);
  }
  __syncthreads();

  float vx = 0.f, vy = 0.f, vz = 0.f, vw = 0.f;

  #pragma unroll
  for (int k = 0; k < KC_; ++k) {
    const int p = (blockIdx.x + k * GX_) * 256 + tid;
    const size_t bp = (size_t)b * P_ + p;
    float4 pr = reinterpret_cast<const float4*>(priors)[p];

    float ov;
    int idx;
    if (BIG) {
      uint2 v = pb[bp];
      ov = __uint_as_float(v.x);
      idx = (int)v.y;
    } else {
      float px1 = pr.x - pr.z * 0.5f, py1 = pr.y - pr.w * 0.5f;
      float px2 = pr.x + pr.z * 0.5f, py2 = pr.y + pr.w * 0.5f;
      float parea = (px2 - px1) * (py2 - py1);
      float bov = -1.f;
      int bidx = 0;
      #pragma unroll 8
      for (int o = 0; o < O_; ++o) {
        float iw = fmaxf(fminf(tx2[o], px2) - fmaxf(tx1[o], px1), 0.f);
        float ih = fmaxf(fminf(ty2[o], py2) - fmaxf(ty1[o], py1), 0.f);
        float inter = iw * ih;
        float iou = inter * frcp(tarea[o] + parea - inter);
        if (iou > bov) { bov = iou; bidx = o; }
      }
      int fi = -1;
      #pragma unroll
      for (int j = 0; j < O_; ++j)
        if (fprior[j] == (unsigned)p) fi = j;  // last j wins
      ov = bov; idx = bidx;
      if (fi >= 0) { idx = fi; ov = 2.0f; }
    }

    const bool pos = !(ov < THRESH_);            // conf_raw != 0
    const bool pos1 = pos && (tlbl[idx] > 0.f);  // conf_raw > 0

    // focal loss (all priors)
    float2 cf = reinterpret_cast<const float2*>(conf_data)[bp];
    float mx = fmaxf(cf.x, cf.y);
    float lse = mx + __logf(1.f + __expf(-fabsf(cf.x - cf.y)));
    float logpt = (pos ? cf.y : cf.x) - lse;
    float pt = __expf(logpt);
    float om = 1.f - pt;
    vy += -ALPHA_ * om * sqrtf(om) * logpt;  // (1-pt)^1.5

    if (pos) {
      float4 loc = reinterpret_cast<const float4*>(loc_data)[bp];
      float dx = pr.x + loc.x * VAR0 * pr.z;
      float dy = pr.y + loc.y * VAR0 * pr.w;
      float dw = pr.z * __expf(loc.z * VAR1);
      float dh = pr.w * __expf(loc.w * VAR1);
      float b1x1 = dx - dw * 0.5f, b1y1 = dy - dh * 0.5f;
      float b1x2 = dx + dw * 0.5f, b1y2 = dy + dh * 0.5f;
      float b2x1 = tx1[idx], b2y1 = ty1[idx], b2x2 = tx2[idx], b2y2 = ty2[idx];
      float a1 = (b1x2 - b1x1) * (b1y2 - b1y1);
      float a2 = (b2x2 - b2x1) * (b2y2 - b2y1);
      float iw = fmaxf(fminf(b1x2, b2x2) - fmaxf(b1x1, b2x1), 0.f);
      float ih = fmaxf(fminf(b1y2, b2y2) - fmaxf(b1y1, b2y1), 0.f);
      float inter = iw * ih;
      float uni = a1 + a2 - inter;
      float iou = inter * frcp(uni + EPS_);
      float ew = fmaxf(b1x2, b2x2) - fminf(b1x1, b2x1);
      float eh = fmaxf(b1y2, b2y2) - fminf(b1y1, b2y1);
      float enc = ew * eh;
      float g = iou - (enc - uni) * frcp(enc + EPS_);
      vx += 1.f - g;
    }
    if (pos1) {
      vw += 1.f;
      const float* lmrow = landm_data + bp * 10;
      float rw = frcp(VAR0 * pr.z);
      float rh = frcp(VAR0 * pr.w);
      float llm = 0.f;
      #pragma unroll
      for (int q = 0; q < 5; ++q) {
        float2 d = *reinterpret_cast<const float2*>(lmrow + q * 2);
        float ex = d.x - (tlm[idx][2 * q] - pr.x) * rw;
        float ey = d.y - (tlm[idx][2 * q + 1] - pr.y) * rh;
        float ax = fabsf(ex), ay = fabsf(ey);
        llm += (ax < 1.f) ? 0.5f * ex * ex : ax - 0.5f;
        llm += (ay < 1.f) ? 0.5f * ey * ey : ay - 0.5f;
      }
      vz += llm;
    }
  }

  // block reduce -> one float4 partial per block, no atomics
  #pragma unroll
  for (int i = 32; i > 0; i >>= 1) {
    vx += __shfl_xor(vx, i);
    vy += __shfl_xor(vy, i);
    vz += __shfl_xor(vz, i);
    vw += __shfl_xor(vw, i);
  }
  const int wave = tid >> 6, lane = tid & 63;
  if (lane == 0) wsum[wave] = make_float4(vx, vy, vz, vw);
  __syncthreads();
  if (tid == 0) {
    float sx = 0.f, sy = 0.f, sz = 0.f, sw = 0.f;
    #pragma unroll
    for (int w = 0; w < 4; ++w) {
      sx += wsum[w].x; sy += wsum[w].y; sz += wsum[w].z; sw += wsum[w].w;
    }
    ws->part[(size_t)blockIdx.y * GX_ + blockIdx.x] = make_float4(sx, sy, sz, sw);
  }
}

// ------- kernel 3: final reduction ------------------------------------------
__global__ __launch_bounds__(256) void k_final(const WSHdr* __restrict__ ws,
                                               float* __restrict__ out) {
  __shared__ double sh[4][4];
  const int tid = threadIdx.x;
  double sx = 0.0, sy = 0.0, sz = 0.0, sw = 0.0;
  for (int i = tid; i < GX_ * B_; i += 256) {
    float4 v = ws->part[i];
    sx += v.x; sy += v.y; sz += v.z; sw += v.w;
  }
  #pragma unroll
  for (int i = 32; i > 0; i >>= 1) {
    sx += __shfl_xor(sx, i);
    sy += __shfl_xor(sy, i);
    sz += __shfl_xor(sz, i);
    sw += __shfl_xor(sw, i);
  }
  const int wave = tid >> 6, lane = tid & 63;
  if (lane == 0) { sh[wave][0] = sx; sh[wave][1] = sy; sh[wave][2] = sz; sh[wave][3] = sw; }
  __syncthreads();
  if (tid == 0) {
    double ax = 0, ay = 0, az = 0, aw = 0;
    #pragma unroll
    for (int w = 0; w < 4; ++w) { ax += sh[w][0]; ay += sh[w][1]; az += sh[w][2]; aw += sh[w][3]; }
    double n1 = aw < 1.0 ? 1.0 : aw;
    out[0] = (float)(2.0 * ax / n1);  // LOC_W
    out[1] = (float)(ay / n1);
    out[2] = (float)(az / n1);        // LANDM_W
  }
}

extern "C" void kernel_launch(void* const* d_in, const int* in_sizes, int n_in,
                              void* d_out, int out_size, void* d_ws, size_t ws_size,
                              hipStream_t stream) {
  (void)in_sizes; (void)n_in; (void)out_size;
  const float* loc     = (const float*)d_in[0];
  const float* conf    = (const float*)d_in[1];
  const float* landm   = (const float*)d_in[2];
  const float* priors  = (const float*)d_in[3];
  const float* targets = (const float*)d_in[4];
  WSHdr* ws = (WSHdr*)d_ws;
  uint2* pb = (uint2*)((char*)d_ws + sizeof(WSHdr));
  float* out = (float*)d_out;
  const bool big = ws_size >= sizeof(WSHdr) + (size_t)B_ * P_ * sizeof(uint2);

  hipLaunchKernelGGL(init_ws, dim3(4), dim3(256), 0, stream, ws);
  dim3 grid(GX_, B_);
  if (big) {
    hipLaunchKernelGGL(k_match<true>, grid, dim3(256), 0, stream, priors, targets, ws, pb);
    hipLaunchKernelGGL(k_forced, dim3(1), dim3(64), 0, stream, ws, pb);
    hipLaunchKernelGGL(k_loss<true>, grid, dim3(256), 0, stream,
                       loc, conf, landm, priors, targets, ws, pb);
  } else {
    hipLaunchKernelGGL(k_match<false>, grid, dim3(256), 0, stream, priors, targets, ws, pb);
    hipLaunchKernelGGL(k_loss<false>, grid, dim3(256), 0, stream,
                       loc, conf, landm, priors, targets, ws, pb);
  }
  hipLaunchKernelGGL(k_final, dim3(1), dim3(256), 0, stream, ws, out);
}

// Round 4
// 91.036 us; speedup vs baseline: 1.8345x; 1.8345x over previous
//
#include <hip/hip_runtime.h>
#include <cstdint>

#define B_ 32
#define P_ 65536
#define O_ 32
#define GX_ 64            // grid.x; each block handles KC_ chunks of 256 priors
#define KC_ 4             // (P_/256)/GX_
#define THRESH_ 0.35f
#define VAR0 0.1f
#define VAR1 0.2f
#define EPS_ 1e-7f
#define ALPHA_ 0.25f

struct WSHdr {
  unsigned long long gkey[B_ * O_];  // per (b,o): packed (iou_bits<<32)|(~p)
  float4 part[GX_ * B_];             // per-block partials (ll, lc, llm, n1)
};
// BIG layout: WSHdr followed by uint2 pb[B_*P_]  ({iou_bits, best_truth_idx})

__device__ __forceinline__ float frcp(float x) { return __builtin_amdgcn_rcpf(x); }

__device__ __forceinline__ unsigned long long shflxor_u64(unsigned long long v, int m) {
  unsigned lo = (unsigned)v, hi = (unsigned)(v >> 32);
  lo = __shfl_xor(lo, m, 64);
  hi = __shfl_xor(hi, m, 64);
  return ((unsigned long long)hi << 32) | lo;
}

__global__ void init_ws(WSHdr* ws) {
  int t = blockIdx.x * blockDim.x + threadIdx.x;
  if (t < B_ * O_) ws->gkey[t] = 0ull;
}

// ------- kernel 1: IoU pass — per-truth argmax + (BIG) per-prior best -------
template <bool BIG>
__global__ __launch_bounds__(256) void k_match(const float* __restrict__ priors,
                                               const float* __restrict__ targets,
                                               WSHdr* __restrict__ ws,
                                               uint2* __restrict__ pb) {
  __shared__ float tsh[O_][5];               // x1,y1,x2,y2,area
  __shared__ unsigned long long lkey[O_];
  const int b = blockIdx.y;
  const int tid = threadIdx.x;
  const int lane = tid & 63;
  if (tid < O_) {
    const float* trow = targets + ((size_t)b * O_ + tid) * 15;
    float x1 = trow[0], y1 = trow[1], x2 = trow[2], y2 = trow[3];
    tsh[tid][0] = x1; tsh[tid][1] = y1; tsh[tid][2] = x2; tsh[tid][3] = y2;
    tsh[tid][4] = (x2 - x1) * (y2 - y1);
    lkey[tid] = 0xFFFFFFFFull;               // key(iou=0, p=0)
  }
  __syncthreads();

  // this thread's KC_ priors, in registers
  float px1[KC_], py1[KC_], px2[KC_], py2[KC_], pa[KC_];
  float bov[KC_];
  int bidx[KC_];
  unsigned pidx[KC_];
  #pragma unroll
  for (int k = 0; k < KC_; ++k) {
    unsigned p = (unsigned)((blockIdx.x + k * GX_) * 256 + tid);
    pidx[k] = p;
    float4 pr = reinterpret_cast<const float4*>(priors)[p];
    px1[k] = pr.x - pr.z * 0.5f; py1[k] = pr.y - pr.w * 0.5f;
    px2[k] = pr.x + pr.z * 0.5f; py2[k] = pr.y + pr.w * 0.5f;
    pa[k] = (px2[k] - px1[k]) * (py2[k] - py1[k]);
    bov[k] = -1.f; bidx[k] = 0;
  }

  #pragma unroll 4
  for (int o = 0; o < O_; ++o) {
    const float x1 = tsh[o][0], y1 = tsh[o][1], x2 = tsh[o][2], y2 = tsh[o][3];
    const float ta = tsh[o][4];
    float tiou = 0.f;
    unsigned tp = 0;
    #pragma unroll
    for (int k = 0; k < KC_; ++k) {
      float iw = fmaxf(fminf(x2, px2[k]) - fmaxf(x1, px1[k]), 0.f);
      float ih = fmaxf(fminf(y2, py2[k]) - fmaxf(y1, py1[k]), 0.f);
      float inter = iw * ih;
      float iou = inter * frcp(ta + pa[k] - inter);
      if (iou > bov[k]) { bov[k] = iou; bidx[k] = o; }  // first-occurrence (o asc)
      if (iou > tiou)   { tiou = iou; tp = pidx[k]; }   // first-occurrence (p asc)
    }
    // wave-wide argmax via butterfly on packed 64-bit key (exact tie-break)
    unsigned long long key = ((unsigned long long)__float_as_uint(tiou) << 32) |
                             (unsigned long long)(0xFFFFFFFFu - tp);
    #pragma unroll
    for (int s = 32; s >= 1; s >>= 1) {
      unsigned long long other = shflxor_u64(key, s);
      if (other > key) key = other;
    }
    if (lane == 0) atomicMax(&lkey[o], key);
  }

  if (BIG) {
    #pragma unroll
    for (int k = 0; k < KC_; ++k)
      pb[(size_t)b * P_ + pidx[k]] = make_uint2(__float_as_uint(bov[k]), (unsigned)bidx[k]);
  }
  __syncthreads();
  if (tid < O_) atomicMax(&ws->gkey[(size_t)b * O_ + tid], lkey[tid]);
}

// ------- kernel 1b (BIG): apply forced matches, last-j-wins ------------------
__global__ void k_forced(const WSHdr* __restrict__ ws, uint2* __restrict__ pb) {
  int b = threadIdx.x;
  if (b >= B_) return;
  for (int j = 0; j < O_; ++j) {  // sequential in one thread => last j wins
    unsigned fp = 0xFFFFFFFFu - (unsigned)(ws->gkey[b * O_ + j] & 0xFFFFFFFFull);
    pb[(size_t)b * P_ + fp] = make_uint2(__float_as_uint(2.0f), (unsigned)j);
  }
}

// ------- kernel 2: losses ----------------------------------------------------
template <bool BIG>
__global__ __launch_bounds__(256) void k_loss(const float* __restrict__ loc_data,
                                              const float* __restrict__ conf_data,
                                              const float* __restrict__ landm_data,
                                              const float* __restrict__ priors,
                                              const float* __restrict__ targets,
                                              WSHdr* __restrict__ ws,
                                              const uint2* __restrict__ pb) {
  __shared__ float tx1[O_], ty1[O_], tx2[O_], ty2[O_], tarea[O_], tlbl[O_];
  __shared__ float tlm[O_][10];
  __shared__ unsigned int fprior[O_];
  __shared__ float4 wsum[4];
  const int b = blockIdx.y;
  const int tid = threadIdx.x;
  if (tid < O_) {
    const float* trow = targets + ((size_t)b * O_ + tid) * 15;
    float x1 = trow[0], y1 = trow[1], x2 = trow[2], y2 = trow[3];
    tx1[tid] = x1; ty1[tid] = y1; tx2[tid] = x2; ty2[tid] = y2;
    tarea[tid] = (x2 - x1) * (y2 - y1);
    #pragma unroll
    for (int k = 0; k < 10; ++k) tlm[tid][k] = trow[4 + k];
    tlbl[tid] = trow[14];
    if (!BIG)
      fprior[tid] = 0xFFFFFFFFu - (unsigned)(ws->gkey[(size_t)b * O_ + tid] & 0xFFFFFFFFull);
  }
  __syncthreads();

  float vx = 0.f, vy = 0.f, vz = 0.f, vw = 0.f;

  #pragma unroll
  for (int k = 0; k < KC_; ++k) {
    const int p = (blockIdx.x + k * GX_) * 256 + tid;
    const size_t bp = (size_t)b * P_ + p;
    float4 pr = reinterpret_cast<const float4*>(priors)[p];

    float ov;
    int idx;
    if (BIG) {
      uint2 v = pb[bp];
      ov = __uint_as_float(v.x);
      idx = (int)v.y;
    } else {
      float px1 = pr.x - pr.z * 0.5f, py1 = pr.y - pr.w * 0.5f;
      float px2 = pr.x + pr.z * 0.5f, py2 = pr.y + pr.w * 0.5f;
      float parea = (px2 - px1) * (py2 - py1);
      float bov = -1.f;
      int bidx = 0;
      #pragma unroll 8
      for (int o = 0; o < O_; ++o) {
        float iw = fmaxf(fminf(tx2[o], px2) - fmaxf(tx1[o], px1), 0.f);
        float ih = fmaxf(fminf(ty2[o], py2) - fmaxf(ty1[o], py1), 0.f);
        float inter = iw * ih;
        float iou = inter * frcp(tarea[o] + parea - inter);
        if (iou > bov) { bov = iou; bidx = o; }
      }
      int fi = -1;
      #pragma unroll
      for (int j = 0; j < O_; ++j)
        if (fprior[j] == (unsigned)p) fi = j;  // last j wins
      ov = bov; idx = bidx;
      if (fi >= 0) { idx = fi; ov = 2.0f; }
    }

    const bool pos = !(ov < THRESH_);            // conf_raw != 0
    const bool pos1 = pos && (tlbl[idx] > 0.f);  // conf_raw > 0

    // focal loss (all priors)
    float2 cf = reinterpret_cast<const float2*>(conf_data)[bp];
    float mx = fmaxf(cf.x, cf.y);
    float lse = mx + __logf(1.f + __expf(-fabsf(cf.x - cf.y)));
    float logpt = (pos ? cf.y : cf.x) - lse;
    float pt = __expf(logpt);
    float om = 1.f - pt;
    vy += -ALPHA_ * om * sqrtf(om) * logpt;  // (1-pt)^1.5

    if (pos) {
      float4 loc = reinterpret_cast<const float4*>(loc_data)[bp];
      float dx = pr.x + loc.x * VAR0 * pr.z;
      float dy = pr.y + loc.y * VAR0 * pr.w;
      float dw = pr.z * __expf(loc.z * VAR1);
      float dh = pr.w * __expf(loc.w * VAR1);
      float b1x1 = dx - dw * 0.5f, b1y1 = dy - dh * 0.5f;
      float b1x2 = dx + dw * 0.5f, b1y2 = dy + dh * 0.5f;
      float b2x1 = tx1[idx], b2y1 = ty1[idx], b2x2 = tx2[idx], b2y2 = ty2[idx];
      float a1 = (b1x2 - b1x1) * (b1y2 - b1y1);
      float a2 = (b2x2 - b2x1) * (b2y2 - b2y1);
      float iw = fmaxf(fminf(b1x2, b2x2) - fmaxf(b1x1, b2x1), 0.f);
      float ih = fmaxf(fminf(b1y2, b2y2) - fmaxf(b1y1, b2y1), 0.f);
      float inter = iw * ih;
      float uni = a1 + a2 - inter;
      float iou = inter * frcp(uni + EPS_);
      float ew = fmaxf(b1x2, b2x2) - fminf(b1x1, b2x1);
      float eh = fmaxf(b1y2, b2y2) - fminf(b1y1, b2y1);
      float enc = ew * eh;
      float g = iou - (enc - uni) * frcp(enc + EPS_);
      vx += 1.f - g;
    }
    if (pos1) {
      vw += 1.f;
      const float* lmrow = landm_data + bp * 10;
      float rw = frcp(VAR0 * pr.z);
      float rh = frcp(VAR0 * pr.w);
      float llm = 0.f;
      #pragma unroll
      for (int q = 0; q < 5; ++q) {
        float2 d = *reinterpret_cast<const float2*>(lmrow + q * 2);
        float ex = d.x - (tlm[idx][2 * q] - pr.x) * rw;
        float ey = d.y - (tlm[idx][2 * q + 1] - pr.y) * rh;
        float ax = fabsf(ex), ay = fabsf(ey);
        llm += (ax < 1.f) ? 0.5f * ex * ex : ax - 0.5f;
        llm += (ay < 1.f) ? 0.5f * ey * ey : ay - 0.5f;
      }
      vz += llm;
    }
  }

  // block reduce -> one float4 partial per block, no atomics
  #pragma unroll
  for (int i = 32; i > 0; i >>= 1) {
    vx += __shfl_xor(vx, i);
    vy += __shfl_xor(vy, i);
    vz += __shfl_xor(vz, i);
    vw += __shfl_xor(vw, i);
  }
  const int wave = tid >> 6, lane = tid & 63;
  if (lane == 0) wsum[wave] = make_float4(vx, vy, vz, vw);
  __syncthreads();
  if (tid == 0) {
    float sx = 0.f, sy = 0.f, sz = 0.f, sw = 0.f;
    #pragma unroll
    for (int w = 0; w < 4; ++w) {
      sx += wsum[w].x; sy += wsum[w].y; sz += wsum[w].z; sw += wsum[w].w;
    }
    ws->part[(size_t)blockIdx.y * GX_ + blockIdx.x] = make_float4(sx, sy, sz, sw);
  }
}

// ------- kernel 3: final reduction ------------------------------------------
__global__ __launch_bounds__(256) void k_final(const WSHdr* __restrict__ ws,
                                               float* __restrict__ out) {
  __shared__ double sh[4][4];
  const int tid = threadIdx.x;
  double sx = 0.0, sy = 0.0, sz = 0.0, sw = 0.0;
  for (int i = tid; i < GX_ * B_; i += 256) {
    float4 v = ws->part[i];
    sx += v.x; sy += v.y; sz += v.z; sw += v.w;
  }
  #pragma unroll
  for (int i = 32; i > 0; i >>= 1) {
    sx += __shfl_xor(sx, i);
    sy += __shfl_xor(sy, i);
    sz += __shfl_xor(sz, i);
    sw += __shfl_xor(sw, i);
  }
  const int wave = tid >> 6, lane = tid & 63;
  if (lane == 0) { sh[wave][0] = sx; sh[wave][1] = sy; sh[wave][2] = sz; sh[wave][3] = sw; }
  __syncthreads();
  if (tid == 0) {
    double ax = 0, ay = 0, az = 0, aw = 0;
    #pragma unroll
    for (int w = 0; w < 4; ++w) { ax += sh[w][0]; ay += sh[w][1]; az += sh[w][2]; aw += sh[w][3]; }
    double n1 = aw < 1.0 ? 1.0 : aw;
    out[0] = (float)(2.0 * ax / n1);  // LOC_W
    out[1] = (float)(ay / n1);
    out[2] = (float)(az / n1);        // LANDM_W
  }
}

extern "C" void kernel_launch(void* const* d_in, const int* in_sizes, int n_in,
                              void* d_out, int out_size, void* d_ws, size_t ws_size,
                              hipStream_t stream) {
  (void)in_sizes; (void)n_in; (void)out_size;
  const float* loc     = (const float*)d_in[0];
  const float* conf    = (const float*)d_in[1];
  const float* landm   = (const float*)d_in[2];
  const float* priors  = (const float*)d_in[3];
  const float* targets = (const float*)d_in[4];
  WSHdr* ws = (WSHdr*)d_ws;
  uint2* pb = (uint2*)((char*)d_ws + sizeof(WSHdr));
  float* out = (float*)d_out;
  const bool big = ws_size >= sizeof(WSHdr) + (size_t)B_ * P_ * sizeof(uint2);

  hipLaunchKernelGGL(init_ws, dim3(4), dim3(256), 0, stream, ws);
  dim3 grid(GX_, B_);
  if (big) {
    hipLaunchKernelGGL(k_match<true>, grid, dim3(256), 0, stream, priors, targets, ws, pb);
    hipLaunchKernelGGL(k_forced, dim3(1), dim3(64), 0, stream, ws, pb);
    hipLaunchKernelGGL(k_loss<true>, grid, dim3(256), 0, stream,
                       loc, conf, landm, priors, targets, ws, pb);
  } else {
    hipLaunchKernelGGL(k_match<false>, grid, dim3(256), 0, stream, priors, targets, ws, pb);
    hipLaunchKernelGGL(k_loss<false>, grid, dim3(256), 0, stream,
                       loc, conf, landm, priors, targets, ws, pb);
  }
  hipLaunchKernelGGL(k_final, dim3(1), dim3(256), 0, stream, ws, out);
}

// Round 5
// 79.871 us; speedup vs baseline: 2.0909x; 1.1398x over previous
//
#include <hip/hip_runtime.h>
#include <cstdint>

#define B_ 32
#define P_ 65536
#define O_ 32
#define GX_ 64            // grid.x; each block handles KC_ chunks of 256 priors
#define KC_ 4             // (P_/256)/GX_
#define THRESH_ 0.35f
#define VAR0 0.1f
#define VAR1 0.2f
#define EPS_ 1e-7f
#define ALPHA_ 0.25f

struct WSHdr {
  unsigned long long gkey[B_ * O_];  // per (b,o): packed (iou_bits<<32)|(~p)
  float4 part[GX_ * B_];             // per-block partials (ll, lc, llm, n1)
};
// BIG layout: WSHdr followed by uint2 pb[B_*P_]  ({iou_bits, best_truth_idx})

__device__ __forceinline__ float frcp(float x) { return __builtin_amdgcn_rcpf(x); }

// u64 max with a DPP-shifted partner (row_ror) — full-rate VALU, no LDS pipe.
template <int CTRL>
__device__ __forceinline__ unsigned long long dpp_max_u64(unsigned long long k) {
  int lo = __builtin_amdgcn_update_dpp((int)(unsigned)k, (int)(unsigned)k,
                                       CTRL, 0xF, 0xF, false);
  int hi = __builtin_amdgcn_update_dpp((int)(k >> 32), (int)(k >> 32),
                                       CTRL, 0xF, 0xF, false);
  unsigned long long o = ((unsigned long long)(unsigned)hi << 32) | (unsigned)lo;
  return o > k ? o : k;
}

__global__ void init_ws(WSHdr* ws) {
  int t = blockIdx.x * blockDim.x + threadIdx.x;
  if (t < B_ * O_) ws->gkey[t] = 0ull;
}

// ------- kernel 1: IoU pass — per-truth argmax + (BIG) per-prior best -------
template <bool BIG>
__global__ __launch_bounds__(256, 8) void k_match(const float* __restrict__ priors,
                                                  const float* __restrict__ targets,
                                                  WSHdr* __restrict__ ws,
                                                  uint2* __restrict__ pb) {
  __shared__ float tsh[O_][5];                  // x1,y1,x2,y2,area
  __shared__ unsigned long long kq[O_][17];     // 16 row-partials + pad (bank-free)
  const int b = blockIdx.y;
  const int tid = threadIdx.x;
  const int lane = tid & 63, wid = tid >> 6;
  if (tid < O_) {
    const float* trow = targets + ((size_t)b * O_ + tid) * 15;
    float x1 = trow[0], y1 = trow[1], x2 = trow[2], y2 = trow[3];
    tsh[tid][0] = x1; tsh[tid][1] = y1; tsh[tid][2] = x2; tsh[tid][3] = y2;
    tsh[tid][4] = (x2 - x1) * (y2 - y1);
  }
  __syncthreads();

  // this thread's KC_ priors, in registers
  float px1[KC_], py1[KC_], px2[KC_], py2[KC_], pa[KC_], bov[KC_];
  int bidx[KC_];
  unsigned pinv[KC_];
  #pragma unroll
  for (int k = 0; k < KC_; ++k) {
    unsigned p = (unsigned)((blockIdx.x + k * GX_) * 256 + tid);
    pinv[k] = 0xFFFFFFFFu - p;
    float4 pr = reinterpret_cast<const float4*>(priors)[p];
    px1[k] = pr.x - pr.z * 0.5f; py1[k] = pr.y - pr.w * 0.5f;
    px2[k] = pr.x + pr.z * 0.5f; py2[k] = pr.y + pr.w * 0.5f;
    pa[k] = (px2[k] - px1[k]) * (py2[k] - py1[k]);
    bov[k] = -1.f; bidx[k] = 0;
  }

  #pragma unroll 4
  for (int o = 0; o < O_; ++o) {
    const float x1 = tsh[o][0], y1 = tsh[o][1], x2 = tsh[o][2], y2 = tsh[o][3];
    const float ta = tsh[o][4];
    float tiou = 0.f;
    unsigned tinv = pinv[0];  // iou==0 contribution: smallest own p
    #pragma unroll
    for (int k = 0; k < KC_; ++k) {
      float iw = fmaxf(fminf(x2, px2[k]) - fmaxf(x1, px1[k]), 0.f);
      float ih = fmaxf(fminf(y2, py2[k]) - fmaxf(y1, py1[k]), 0.f);
      float inter = iw * ih;
      float iou = inter * frcp(ta + pa[k] - inter);
      if (iou > bov[k]) { bov[k] = iou; bidx[k] = o; }  // first occurrence (o asc)
      if (iou > tiou)   { tiou = iou; tinv = pinv[k]; } // first occurrence (p asc)
    }
    // 16-lane row max-reduce via DPP (VALU-rate, no LDS pipe)
    unsigned long long key = ((unsigned long long)__float_as_uint(tiou) << 32) |
                             (unsigned long long)tinv;
    key = dpp_max_u64<0x128>(key);  // row_ror:8
    key = dpp_max_u64<0x124>(key);  // row_ror:4
    key = dpp_max_u64<0x122>(key);  // row_ror:2
    key = dpp_max_u64<0x121>(key);  // row_ror:1
    if ((lane & 15) == 0) kq[o][wid * 4 + (lane >> 4)] = key;
  }

  if (BIG) {
    #pragma unroll
    for (int k = 0; k < KC_; ++k)
      pb[(size_t)b * P_ + (0xFFFFFFFFu - pinv[k])] =
          make_uint2(__float_as_uint(bov[k]), (unsigned)bidx[k]);
  }
  __syncthreads();
  // phase B: 32 threads reduce 16 row-partials each, one global atomic per o
  if (tid < O_) {
    unsigned long long best = kq[tid][0];
    #pragma unroll
    for (int s = 1; s < 16; ++s) {
      unsigned long long v = kq[tid][s];
      if (v > best) best = v;
    }
    atomicMax(&ws->gkey[(size_t)b * O_ + tid], best);
  }
}

// ------- kernel 2: losses (applies forced matches inline) --------------------
template <bool BIG>
__global__ __launch_bounds__(256) void k_loss(const float* __restrict__ loc_data,
                                              const float* __restrict__ conf_data,
                                              const float* __restrict__ landm_data,
                                              const float* __restrict__ priors,
                                              const float* __restrict__ targets,
                                              WSHdr* __restrict__ ws,
                                              const uint2* __restrict__ pb) {
  __shared__ float tx1[O_], ty1[O_], tx2[O_], ty2[O_], tarea[O_], tlbl[O_];
  __shared__ float tlm[O_][10];
  __shared__ unsigned int fprior[O_];
  __shared__ float4 wsum[4];
  const int b = blockIdx.y;
  const int tid = threadIdx.x;
  if (tid < O_) {
    const float* trow = targets + ((size_t)b * O_ + tid) * 15;
    float x1 = trow[0], y1 = trow[1], x2 = trow[2], y2 = trow[3];
    tx1[tid] = x1; ty1[tid] = y1; tx2[tid] = x2; ty2[tid] = y2;
    tarea[tid] = (x2 - x1) * (y2 - y1);
    #pragma unroll
    for (int k = 0; k < 10; ++k) tlm[tid][k] = trow[4 + k];
    tlbl[tid] = trow[14];
    fprior[tid] = 0xFFFFFFFFu - (unsigned)(ws->gkey[(size_t)b * O_ + tid] & 0xFFFFFFFFull);
  }
  __syncthreads();

  float vx = 0.f, vy = 0.f, vz = 0.f, vw = 0.f;

  #pragma unroll
  for (int k = 0; k < KC_; ++k) {
    const int p = (blockIdx.x + k * GX_) * 256 + tid;
    const size_t bp = (size_t)b * P_ + p;
    float4 pr = reinterpret_cast<const float4*>(priors)[p];

    float ov;
    int idx;
    if (BIG) {
      uint2 v = pb[bp];
      ov = __uint_as_float(v.x);
      idx = (int)v.y;
    } else {
      float px1 = pr.x - pr.z * 0.5f, py1 = pr.y - pr.w * 0.5f;
      float px2 = pr.x + pr.z * 0.5f, py2 = pr.y + pr.w * 0.5f;
      float parea = (px2 - px1) * (py2 - py1);
      float bov = -1.f;
      int bidx = 0;
      #pragma unroll 8
      for (int o = 0; o < O_; ++o) {
        float iw = fmaxf(fminf(tx2[o], px2) - fmaxf(tx1[o], px1), 0.f);
        float ih = fmaxf(fminf(ty2[o], py2) - fmaxf(ty1[o], py1), 0.f);
        float inter = iw * ih;
        float iou = inter * frcp(tarea[o] + parea - inter);
        if (iou > bov) { bov = iou; bidx = o; }
      }
      ov = bov; idx = bidx;
    }
    // forced matches: last j wins (XLA sequential scatter semantics)
    int fi = -1;
    #pragma unroll
    for (int j = 0; j < O_; ++j)
      if (fprior[j] == (unsigned)p) fi = j;
    if (fi >= 0) { idx = fi; ov = 2.0f; }

    const bool pos = !(ov < THRESH_);            // conf_raw != 0
    const bool pos1 = pos && (tlbl[idx] > 0.f);  // conf_raw > 0

    // focal loss (all priors)
    float2 cf = reinterpret_cast<const float2*>(conf_data)[bp];
    float mx = fmaxf(cf.x, cf.y);
    float lse = mx + __logf(1.f + __expf(-fabsf(cf.x - cf.y)));
    float logpt = (pos ? cf.y : cf.x) - lse;
    float pt = __expf(logpt);
    float om = 1.f - pt;
    vy += -ALPHA_ * om * sqrtf(om) * logpt;  // (1-pt)^1.5

    if (pos) {
      float4 loc = reinterpret_cast<const float4*>(loc_data)[bp];
      float dx = pr.x + loc.x * VAR0 * pr.z;
      float dy = pr.y + loc.y * VAR0 * pr.w;
      float dw = pr.z * __expf(loc.z * VAR1);
      float dh = pr.w * __expf(loc.w * VAR1);
      float b1x1 = dx - dw * 0.5f, b1y1 = dy - dh * 0.5f;
      float b1x2 = dx + dw * 0.5f, b1y2 = dy + dh * 0.5f;
      float b2x1 = tx1[idx], b2y1 = ty1[idx], b2x2 = tx2[idx], b2y2 = ty2[idx];
      float a1 = (b1x2 - b1x1) * (b1y2 - b1y1);
      float a2 = (b2x2 - b2x1) * (b2y2 - b2y1);
      float iw = fmaxf(fminf(b1x2, b2x2) - fmaxf(b1x1, b2x1), 0.f);
      float ih = fmaxf(fminf(b1y2, b2y2) - fmaxf(b1y1, b2y1), 0.f);
      float inter = iw * ih;
      float uni = a1 + a2 - inter;
      float iou = inter * frcp(uni + EPS_);
      float ew = fmaxf(b1x2, b2x2) - fminf(b1x1, b2x1);
      float eh = fmaxf(b1y2, b2y2) - fminf(b1y1, b2y1);
      float enc = ew * eh;
      float g = iou - (enc - uni) * frcp(enc + EPS_);
      vx += 1.f - g;
    }
    if (pos1) {
      vw += 1.f;
      const float* lmrow = landm_data + bp * 10;
      float rw = frcp(VAR0 * pr.z);
      float rh = frcp(VAR0 * pr.w);
      float llm = 0.f;
      #pragma unroll
      for (int q = 0; q < 5; ++q) {
        float2 d = *reinterpret_cast<const float2*>(lmrow + q * 2);
        float ex = d.x - (tlm[idx][2 * q] - pr.x) * rw;
        float ey = d.y - (tlm[idx][2 * q + 1] - pr.y) * rh;
        float ax = fabsf(ex), ay = fabsf(ey);
        llm += (ax < 1.f) ? 0.5f * ex * ex : ax - 0.5f;
        llm += (ay < 1.f) ? 0.5f * ey * ey : ay - 0.5f;
      }
      vz += llm;
    }
  }

  // block reduce -> one float4 partial per block, no atomics
  #pragma unroll
  for (int i = 32; i > 0; i >>= 1) {
    vx += __shfl_xor(vx, i);
    vy += __shfl_xor(vy, i);
    vz += __shfl_xor(vz, i);
    vw += __shfl_xor(vw, i);
  }
  const int wave = tid >> 6, lane = tid & 63;
  if (lane == 0) wsum[wave] = make_float4(vx, vy, vz, vw);
  __syncthreads();
  if (tid == 0) {
    float sx = 0.f, sy = 0.f, sz = 0.f, sw = 0.f;
    #pragma unroll
    for (int w = 0; w < 4; ++w) {
      sx += wsum[w].x; sy += wsum[w].y; sz += wsum[w].z; sw += wsum[w].w;
    }
    ws->part[(size_t)blockIdx.y * GX_ + blockIdx.x] = make_float4(sx, sy, sz, sw);
  }
}

// ------- kernel 3: final reduction ------------------------------------------
__global__ __launch_bounds__(256) void k_final(const WSHdr* __restrict__ ws,
                                               float* __restrict__ out) {
  __shared__ double sh[4][4];
  const int tid = threadIdx.x;
  double sx = 0.0, sy = 0.0, sz = 0.0, sw = 0.0;
  for (int i = tid; i < GX_ * B_; i += 256) {
    float4 v = ws->part[i];
    sx += v.x; sy += v.y; sz += v.z; sw += v.w;
  }
  #pragma unroll
  for (int i = 32; i > 0; i >>= 1) {
    sx += __shfl_xor(sx, i);
    sy += __shfl_xor(sy, i);
    sz += __shfl_xor(sz, i);
    sw += __shfl_xor(sw, i);
  }
  const int wave = tid >> 6, lane = tid & 63;
  if (lane == 0) { sh[wave][0] = sx; sh[wave][1] = sy; sh[wave][2] = sz; sh[wave][3] = sw; }
  __syncthreads();
  if (tid == 0) {
    double ax = 0, ay = 0, az = 0, aw = 0;
    #pragma unroll
    for (int w = 0; w < 4; ++w) { ax += sh[w][0]; ay += sh[w][1]; az += sh[w][2]; aw += sh[w][3]; }
    double n1 = aw < 1.0 ? 1.0 : aw;
    out[0] = (float)(2.0 * ax / n1);  // LOC_W
    out[1] = (float)(ay / n1);
    out[2] = (float)(az / n1);        // LANDM_W
  }
}

extern "C" void kernel_launch(void* const* d_in, const int* in_sizes, int n_in,
                              void* d_out, int out_size, void* d_ws, size_t ws_size,
                              hipStream_t stream) {
  (void)in_sizes; (void)n_in; (void)out_size;
  const float* loc     = (const float*)d_in[0];
  const float* conf    = (const float*)d_in[1];
  const float* landm   = (const float*)d_in[2];
  const float* priors  = (const float*)d_in[3];
  const float* targets = (const float*)d_in[4];
  WSHdr* ws = (WSHdr*)d_ws;
  uint2* pb = (uint2*)((char*)d_ws + sizeof(WSHdr));
  float* out = (float*)d_out;
  const bool big = ws_size >= sizeof(WSHdr) + (size_t)B_ * P_ * sizeof(uint2);

  hipLaunchKernelGGL(init_ws, dim3(4), dim3(256), 0, stream, ws);
  dim3 grid(GX_, B_);
  if (big) {
    hipLaunchKernelGGL(k_match<true>, grid, dim3(256), 0, stream, priors, targets, ws, pb);
    hipLaunchKernelGGL(k_loss<true>, grid, dim3(256), 0, stream,
                       loc, conf, landm, priors, targets, ws, pb);
  } else {
    hipLaunchKernelGGL(k_match<false>, grid, dim3(256), 0, stream, priors, targets, ws, pb);
    hipLaunchKernelGGL(k_loss<false>, grid, dim3(256), 0, stream,
                       loc, conf, landm, priors, targets, ws, pb);
  }
  hipLaunchKernelGGL(k_final, dim3(1), dim3(256), 0, stream, ws, out);
}

// Round 6
// 76.997 us; speedup vs baseline: 2.1690x; 1.0373x over previous
//
#include <hip/hip_runtime.h>
#include <cstdint>

#define B_ 32
#define P_ 65536
#define O_ 32
#define GX_ 64            // grid.x; each block handles KC_ chunks of 256 priors
#define KC_ 4             // (P_/256)/GX_
#define THRESH_ 0.35f
#define VAR0 0.1f
#define VAR1 0.2f
#define EPS_ 1e-7f
#define ALPHA_ 0.25f

struct WSHdr {
  unsigned long long gkey[B_ * O_];  // per (b,o): packed (iou_bits<<32)|(~p)
  float4 part[GX_ * B_];             // per-block partials (ll, lc, llm, n1)
};
// BIG layout: WSHdr followed by uint2 pb[B_*P_]  ({iou_bits, best_truth_idx})

__device__ __forceinline__ float frcp(float x) { return __builtin_amdgcn_rcpf(x); }

// fused-DPP reduction helpers (row_ror rotation reduce: all 16 lanes get result)
template <int CTRL>
__device__ __forceinline__ float dpp_fmax(float v) {
  int s = __builtin_amdgcn_update_dpp(0, __float_as_int(v), CTRL, 0xF, 0xF, true);
  return fmaxf(v, __int_as_float(s));
}
template <int CTRL>
__device__ __forceinline__ unsigned dpp_umax(unsigned v) {
  unsigned u = (unsigned)__builtin_amdgcn_update_dpp(0, (int)v, CTRL, 0xF, 0xF, true);
  return u > v ? u : v;
}

__global__ void init_ws(WSHdr* ws) {
  int t = blockIdx.x * blockDim.x + threadIdx.x;
  if (t < B_ * O_) ws->gkey[t] = 0ull;
}

// ------- kernel 1: IoU pass — per-truth argmax + (BIG) per-prior best -------
template <bool BIG>
__global__ __launch_bounds__(256) void k_match(const float* __restrict__ priors,
                                               const float* __restrict__ targets,
                                               WSHdr* __restrict__ ws,
                                               uint2* __restrict__ pb) {
  __shared__ float tsh[O_][5];                  // x1,y1,x2,y2,area
  __shared__ unsigned long long kq[O_][17];     // 16 row-partials + pad
  const int b = blockIdx.y;
  const int tid = threadIdx.x;
  const int lane = tid & 63, wid = tid >> 6;
  if (tid < O_) {
    const float* trow = targets + ((size_t)b * O_ + tid) * 15;
    float x1 = trow[0], y1 = trow[1], x2 = trow[2], y2 = trow[3];
    tsh[tid][0] = x1; tsh[tid][1] = y1; tsh[tid][2] = x2; tsh[tid][3] = y2;
    tsh[tid][4] = (x2 - x1) * (y2 - y1);
  }
  __syncthreads();

  // this thread's KC_ priors, in registers
  float px1[KC_], py1[KC_], px2[KC_], py2[KC_], pa[KC_], bov[KC_];
  int bidx[KC_];
  unsigned pinv[KC_];
  #pragma unroll
  for (int k = 0; k < KC_; ++k) {
    unsigned p = (unsigned)((blockIdx.x + k * GX_) * 256 + tid);
    pinv[k] = 0xFFFFFFFFu - p;
    float4 pr = reinterpret_cast<const float4*>(priors)[p];
    px1[k] = pr.x - pr.z * 0.5f; py1[k] = pr.y - pr.w * 0.5f;
    px2[k] = pr.x + pr.z * 0.5f; py2[k] = pr.y + pr.w * 0.5f;
    pa[k] = (px2[k] - px1[k]) * (py2[k] - py1[k]);
    bov[k] = -1.f; bidx[k] = 0;
  }

  #pragma unroll 4
  for (int o = 0; o < O_; ++o) {
    const float x1 = tsh[o][0], y1 = tsh[o][1], x2 = tsh[o][2], y2 = tsh[o][3];
    const float ta = tsh[o][4];
    float tiou = 0.f;
    unsigned tinv = pinv[0];  // iou==0 contribution: smallest own p
    #pragma unroll
    for (int k = 0; k < KC_; ++k) {
      float iw = fmaxf(fminf(x2, px2[k]) - fmaxf(x1, px1[k]), 0.f);
      float ih = fmaxf(fminf(y2, py2[k]) - fmaxf(y1, py1[k]), 0.f);
      float inter = iw * ih;
      float iou = inter * frcp(ta + pa[k] - inter);
      if (iou > bov[k]) { bov[k] = iou; bidx[k] = o; }  // first occurrence (o asc)
      if (iou > tiou)   { tiou = iou; tinv = pinv[k]; } // first occurrence (p asc)
    }
    // phase 1: 16-lane row max of iou (fused v_max_f32 dpp, 1 inst/step)
    float m = tiou;
    m = dpp_fmax<0x128>(m);  // row_ror:8
    m = dpp_fmax<0x124>(m);  // row_ror:4
    m = dpp_fmax<0x122>(m);  // row_ror:2
    m = dpp_fmax<0x121>(m);  // row_ror:1
    // phase 2: among lanes achieving the max, take max ~p (= min p)
    unsigned cand = (tiou == m) ? tinv : 0u;
    cand = dpp_umax<0x128>(cand);
    cand = dpp_umax<0x124>(cand);
    cand = dpp_umax<0x122>(cand);
    cand = dpp_umax<0x121>(cand);
    if ((lane & 15) == 0)
      kq[o][wid * 4 + (lane >> 4)] =
          ((unsigned long long)__float_as_uint(m) << 32) | (unsigned long long)cand;
  }

  if (BIG) {
    #pragma unroll
    for (int k = 0; k < KC_; ++k)
      pb[(size_t)b * P_ + (0xFFFFFFFFu - pinv[k])] =
          make_uint2(__float_as_uint(bov[k]), (unsigned)bidx[k]);
  }
  __syncthreads();
  // phase B: 32 threads reduce 16 row-partials each, one global atomic per o
  if (tid < O_) {
    unsigned long long best = kq[tid][0];
    #pragma unroll
    for (int s = 1; s < 16; ++s) {
      unsigned long long v = kq[tid][s];
      if (v > best) best = v;
    }
    atomicMax(&ws->gkey[(size_t)b * O_ + tid], best);
  }
}

// ------- kernel 2: losses (forced matches via LDS byte-map) ------------------
template <bool BIG>
__global__ __launch_bounds__(256) void k_loss(const float* __restrict__ loc_data,
                                              const float* __restrict__ conf_data,
                                              const float* __restrict__ landm_data,
                                              const float* __restrict__ priors,
                                              const float* __restrict__ targets,
                                              WSHdr* __restrict__ ws,
                                              const uint2* __restrict__ pb) {
  __shared__ float tx1[O_], ty1[O_], tx2[O_], ty2[O_], tarea[O_], tlbl[O_];
  __shared__ float tlm[O_][10];
  __shared__ unsigned fp_s[O_];
  __shared__ unsigned char fmap[KC_ * 256];  // forced-truth idx per local prior
  __shared__ float4 wsum[4];
  const int b = blockIdx.y;
  const int tid = threadIdx.x;
  #pragma unroll
  for (int k = 0; k < KC_; ++k) fmap[k * 256 + tid] = 0xFF;
  if (tid < O_) {
    const float* trow = targets + ((size_t)b * O_ + tid) * 15;
    float x1 = trow[0], y1 = trow[1], x2 = trow[2], y2 = trow[3];
    tx1[tid] = x1; ty1[tid] = y1; tx2[tid] = x2; ty2[tid] = y2;
    tarea[tid] = (x2 - x1) * (y2 - y1);
    #pragma unroll
    for (int k = 0; k < 10; ++k) tlm[tid][k] = trow[4 + k];
    tlbl[tid] = trow[14];
    fp_s[tid] = 0xFFFFFFFFu - (unsigned)(ws->gkey[(size_t)b * O_ + tid] & 0xFFFFFFFFull);
  }
  __syncthreads();
  if (tid == 0) {
    // sequential j ascending => last j wins (XLA scatter semantics)
    for (int j = 0; j < O_; ++j) {
      unsigned fp = fp_s[j];
      unsigned c = fp >> 8;                       // global chunk id
      if ((c & (GX_ - 1)) == (unsigned)blockIdx.x)
        fmap[(c >> 6) * 256 + (fp & 255)] = (unsigned char)j;
    }
  }
  __syncthreads();

  float vx = 0.f, vy = 0.f, vz = 0.f, vw = 0.f;

  #pragma unroll
  for (int k = 0; k < KC_; ++k) {
    const int p = (blockIdx.x + k * GX_) * 256 + tid;
    const size_t bp = (size_t)b * P_ + p;
    float4 pr = reinterpret_cast<const float4*>(priors)[p];

    float ov;
    int idx;
    if (BIG) {
      uint2 v = pb[bp];
      ov = __uint_as_float(v.x);
      idx = (int)v.y;
    } else {
      float px1 = pr.x - pr.z * 0.5f, py1 = pr.y - pr.w * 0.5f;
      float px2 = pr.x + pr.z * 0.5f, py2 = pr.y + pr.w * 0.5f;
      float parea = (px2 - px1) * (py2 - py1);
      float bov = -1.f;
      int bidx = 0;
      #pragma unroll 8
      for (int o = 0; o < O_; ++o) {
        float iw = fmaxf(fminf(tx2[o], px2) - fmaxf(tx1[o], px1), 0.f);
        float ih = fmaxf(fminf(ty2[o], py2) - fmaxf(ty1[o], py1), 0.f);
        float inter = iw * ih;
        float iou = inter * frcp(tarea[o] + parea - inter);
        if (iou > bov) { bov = iou; bidx = o; }
      }
      ov = bov; idx = bidx;
    }
    // forced-match override via byte map
    unsigned char fj = fmap[k * 256 + tid];
    if (fj != 0xFF) { idx = (int)fj; ov = 2.0f; }

    const bool pos = !(ov < THRESH_);            // conf_raw != 0
    const bool pos1 = pos && (tlbl[idx] > 0.f);  // conf_raw > 0

    // focal loss (all priors)
    float2 cf = reinterpret_cast<const float2*>(conf_data)[bp];
    float mx = fmaxf(cf.x, cf.y);
    float lse = mx + __logf(1.f + __expf(-fabsf(cf.x - cf.y)));
    float logpt = (pos ? cf.y : cf.x) - lse;
    float pt = __expf(logpt);
    float om = 1.f - pt;
    vy += -ALPHA_ * om * sqrtf(om) * logpt;  // (1-pt)^1.5

    if (pos) {
      float4 loc = reinterpret_cast<const float4*>(loc_data)[bp];
      float dx = pr.x + loc.x * VAR0 * pr.z;
      float dy = pr.y + loc.y * VAR0 * pr.w;
      float dw = pr.z * __expf(loc.z * VAR1);
      float dh = pr.w * __expf(loc.w * VAR1);
      float b1x1 = dx - dw * 0.5f, b1y1 = dy - dh * 0.5f;
      float b1x2 = dx + dw * 0.5f, b1y2 = dy + dh * 0.5f;
      float b2x1 = tx1[idx], b2y1 = ty1[idx], b2x2 = tx2[idx], b2y2 = ty2[idx];
      float a1 = (b1x2 - b1x1) * (b1y2 - b1y1);
      float a2 = (b2x2 - b2x1) * (b2y2 - b2y1);
      float iw = fmaxf(fminf(b1x2, b2x2) - fmaxf(b1x1, b2x1), 0.f);
      float ih = fmaxf(fminf(b1y2, b2y2) - fmaxf(b1y1, b2y1), 0.f);
      float inter = iw * ih;
      float uni = a1 + a2 - inter;
      float iou = inter * frcp(uni + EPS_);
      float ew = fmaxf(b1x2, b2x2) - fminf(b1x1, b2x1);
      float eh = fmaxf(b1y2, b2y2) - fminf(b1y1, b2y1);
      float enc = ew * eh;
      float g = iou - (enc - uni) * frcp(enc + EPS_);
      vx += 1.f - g;
    }
    if (pos1) {
      vw += 1.f;
      const float* lmrow = landm_data + bp * 10;
      float rw = frcp(VAR0 * pr.z);
      float rh = frcp(VAR0 * pr.w);
      float llm = 0.f;
      #pragma unroll
      for (int q = 0; q < 5; ++q) {
        float2 d = *reinterpret_cast<const float2*>(lmrow + q * 2);
        float ex = d.x - (tlm[idx][2 * q] - pr.x) * rw;
        float ey = d.y - (tlm[idx][2 * q + 1] - pr.y) * rh;
        float ax = fabsf(ex), ay = fabsf(ey);
        llm += (ax < 1.f) ? 0.5f * ex * ex : ax - 0.5f;
        llm += (ay < 1.f) ? 0.5f * ey * ey : ay - 0.5f;
      }
      vz += llm;
    }
  }

  // block reduce -> one float4 partial per block, no atomics
  #pragma unroll
  for (int i = 32; i > 0; i >>= 1) {
    vx += __shfl_xor(vx, i);
    vy += __shfl_xor(vy, i);
    vz += __shfl_xor(vz, i);
    vw += __shfl_xor(vw, i);
  }
  const int wave = tid >> 6, lane = tid & 63;
  if (lane == 0) wsum[wave] = make_float4(vx, vy, vz, vw);
  __syncthreads();
  if (tid == 0) {
    float sx = 0.f, sy = 0.f, sz = 0.f, sw = 0.f;
    #pragma unroll
    for (int w = 0; w < 4; ++w) {
      sx += wsum[w].x; sy += wsum[w].y; sz += wsum[w].z; sw += wsum[w].w;
    }
    ws->part[(size_t)blockIdx.y * GX_ + blockIdx.x] = make_float4(sx, sy, sz, sw);
  }
}

// ------- kernel 3: final reduction ------------------------------------------
__global__ __launch_bounds__(256) void k_final(const WSHdr* __restrict__ ws,
                                               float* __restrict__ out) {
  __shared__ double sh[4][4];
  const int tid = threadIdx.x;
  double sx = 0.0, sy = 0.0, sz = 0.0, sw = 0.0;
  for (int i = tid; i < GX_ * B_; i += 256) {
    float4 v = ws->part[i];
    sx += v.x; sy += v.y; sz += v.z; sw += v.w;
  }
  #pragma unroll
  for (int i = 32; i > 0; i >>= 1) {
    sx += __shfl_xor(sx, i);
    sy += __shfl_xor(sy, i);
    sz += __shfl_xor(sz, i);
    sw += __shfl_xor(sw, i);
  }
  const int wave = tid >> 6, lane = tid & 63;
  if (lane == 0) { sh[wave][0] = sx; sh[wave][1] = sy; sh[wave][2] = sz; sh[wave][3] = sw; }
  __syncthreads();
  if (tid == 0) {
    double ax = 0, ay = 0, az = 0, aw = 0;
    #pragma unroll
    for (int w = 0; w < 4; ++w) { ax += sh[w][0]; ay += sh[w][1]; az += sh[w][2]; aw += sh[w][3]; }
    double n1 = aw < 1.0 ? 1.0 : aw;
    out[0] = (float)(2.0 * ax / n1);  // LOC_W
    out[1] = (float)(ay / n1);
    out[2] = (float)(az / n1);        // LANDM_W
  }
}

extern "C" void kernel_launch(void* const* d_in, const int* in_sizes, int n_in,
                              void* d_out, int out_size, void* d_ws, size_t ws_size,
                              hipStream_t stream) {
  (void)in_sizes; (void)n_in; (void)out_size;
  const float* loc     = (const float*)d_in[0];
  const float* conf    = (const float*)d_in[1];
  const float* landm   = (const float*)d_in[2];
  const float* priors  = (const float*)d_in[3];
  const float* targets = (const float*)d_in[4];
  WSHdr* ws = (WSHdr*)d_ws;
  uint2* pb = (uint2*)((char*)d_ws + sizeof(WSHdr));
  float* out = (float*)d_out;
  const bool big = ws_size >= sizeof(WSHdr) + (size_t)B_ * P_ * sizeof(uint2);

  hipLaunchKernelGGL(init_ws, dim3(4), dim3(256), 0, stream, ws);
  dim3 grid(GX_, B_);
  if (big) {
    hipLaunchKernelGGL(k_match<true>, grid, dim3(256), 0, stream, priors, targets, ws, pb);
    hipLaunchKernelGGL(k_loss<true>, grid, dim3(256), 0, stream,
                       loc, conf, landm, priors, targets, ws, pb);
  } else {
    hipLaunchKernelGGL(k_match<false>, grid, dim3(256), 0, stream, priors, targets, ws, pb);
    hipLaunchKernelGGL(k_loss<false>, grid, dim3(256), 0, stream,
                       loc, conf, landm, priors, targets, ws, pb);
  }
  hipLaunchKernelGGL(k_final, dim3(1), dim3(256), 0, stream, ws, out);
}

// Round 7
// 73.170 us; speedup vs baseline: 2.2824x; 1.0523x over previous
//
#include <hip/hip_runtime.h>
#include <cstdint>

#define B_ 32
#define P_ 65536
#define O_ 32
#define GX_ 64            // grid.x; each block handles KC_ chunks of 256 priors
#define KC_ 4             // (P_/256)/GX_
#define THRESH_ 0.35f
#define VAR0 0.1f
#define VAR1 0.2f
#define EPS_ 1e-7f
#define ALPHA_ 0.25f

struct WSHdr {
  unsigned long long gkey[B_ * O_];  // per (b,o): packed (iou_bits<<32)|(~p)
  float4 part[GX_ * B_];             // per-block partials (ll, lc, llm, n1)
  double corr[B_][4];                // per-batch forced-match corrections
};

__device__ __forceinline__ float frcp(float x) { return __builtin_amdgcn_rcpf(x); }

// fused-DPP reduction helpers (row_ror rotation reduce: all 16 lanes get result)
template <int CTRL>
__device__ __forceinline__ float dpp_fmax(float v) {
  int s = __builtin_amdgcn_update_dpp(0, __float_as_int(v), CTRL, 0xF, 0xF, true);
  return fmaxf(v, __int_as_float(s));
}
template <int CTRL>
__device__ __forceinline__ unsigned dpp_umax(unsigned v) {
  unsigned u = (unsigned)__builtin_amdgcn_update_dpp(0, (int)v, CTRL, 0xF, 0xF, true);
  return u > v ? u : v;
}

// ---- shared loss math (used by k_fused AND k_fix: identical expressions) ----
__device__ __forceinline__ float focal_term(float2 cf, bool pos) {
  float mx = fmaxf(cf.x, cf.y);
  float lse = mx + __logf(1.f + __expf(-fabsf(cf.x - cf.y)));
  float logpt = (pos ? cf.y : cf.x) - lse;
  float pt = __expf(logpt);
  float om = 1.f - pt;
  return -ALPHA_ * om * sqrtf(om) * logpt;  // alpha*(1-pt)^1.5*(-logpt)
}

__device__ __forceinline__ float giou_term(float4 pr, float4 loc,
                                           float b2x1, float b2y1,
                                           float b2x2, float b2y2) {
  float dx = pr.x + loc.x * VAR0 * pr.z;
  float dy = pr.y + loc.y * VAR0 * pr.w;
  float dw = pr.z * __expf(loc.z * VAR1);
  float dh = pr.w * __expf(loc.w * VAR1);
  float b1x1 = dx - dw * 0.5f, b1y1 = dy - dh * 0.5f;
  float b1x2 = dx + dw * 0.5f, b1y2 = dy + dh * 0.5f;
  float a1 = (b1x2 - b1x1) * (b1y2 - b1y1);
  float a2 = (b2x2 - b2x1) * (b2y2 - b2y1);
  float iw = fmaxf(fminf(b1x2, b2x2) - fmaxf(b1x1, b2x1), 0.f);
  float ih = fmaxf(fminf(b1y2, b2y2) - fmaxf(b1y1, b2y1), 0.f);
  float inter = iw * ih;
  float uni = a1 + a2 - inter;
  float iou = inter * frcp(uni + EPS_);
  float ew = fmaxf(b1x2, b2x2) - fminf(b1x1, b2x1);
  float eh = fmaxf(b1y2, b2y2) - fminf(b1y1, b2y1);
  float enc = ew * eh;
  float g = iou - (enc - uni) * frcp(enc + EPS_);
  return 1.f - g;
}

__device__ __forceinline__ float landm_term(float4 pr,
                                            const float* __restrict__ lmrow,
                                            const float* __restrict__ tlm_row) {
  float rw = frcp(VAR0 * pr.z);
  float rh = frcp(VAR0 * pr.w);
  float llm = 0.f;
  #pragma unroll
  for (int q = 0; q < 5; ++q) {
    float2 d = *reinterpret_cast<const float2*>(lmrow + q * 2);
    float ex = d.x - (tlm_row[2 * q] - pr.x) * rw;
    float ey = d.y - (tlm_row[2 * q + 1] - pr.y) * rh;
    float ax = fabsf(ex), ay = fabsf(ey);
    llm += (ax < 1.f) ? 0.5f * ex * ex : ax - 0.5f;
    llm += (ay < 1.f) ? 0.5f * ey * ey : ay - 0.5f;
  }
  return llm;
}

__global__ void init_ws(WSHdr* ws) {
  int t = blockIdx.x * blockDim.x + threadIdx.x;
  if (t < B_ * O_) ws->gkey[t] = 0ull;
}

// ------- kernel 1: fused match + unforced losses ----------------------------
__global__ __launch_bounds__(256) void k_fused(const float* __restrict__ loc_data,
                                               const float* __restrict__ conf_data,
                                               const float* __restrict__ landm_data,
                                               const float* __restrict__ priors,
                                               const float* __restrict__ targets,
                                               WSHdr* __restrict__ ws) {
  __shared__ float tsh[O_][5];                  // x1,y1,x2,y2,area
  __shared__ float tlbl[O_];
  __shared__ float tlm[O_][10];
  __shared__ unsigned long long kq[O_][17];     // 16 row-partials + pad
  __shared__ float4 wsum[4];
  const int b = blockIdx.y;
  const int tid = threadIdx.x;
  const int lane = tid & 63, wid = tid >> 6;
  if (tid < O_) {
    const float* trow = targets + ((size_t)b * O_ + tid) * 15;
    float x1 = trow[0], y1 = trow[1], x2 = trow[2], y2 = trow[3];
    tsh[tid][0] = x1; tsh[tid][1] = y1; tsh[tid][2] = x2; tsh[tid][3] = y2;
    tsh[tid][4] = (x2 - x1) * (y2 - y1);
    #pragma unroll
    for (int k = 0; k < 10; ++k) tlm[tid][k] = trow[4 + k];
    tlbl[tid] = trow[14];
  }
  __syncthreads();

  // this thread's KC_ priors (corners), in registers
  float px1[KC_], py1[KC_], px2[KC_], py2[KC_], pa[KC_], bov[KC_];
  int bidx[KC_];
  unsigned pinv[KC_];
  #pragma unroll
  for (int k = 0; k < KC_; ++k) {
    unsigned p = (unsigned)((blockIdx.x + k * GX_) * 256 + tid);
    pinv[k] = 0xFFFFFFFFu - p;
    float4 pr = reinterpret_cast<const float4*>(priors)[p];
    px1[k] = pr.x - pr.z * 0.5f; py1[k] = pr.y - pr.w * 0.5f;
    px2[k] = pr.x + pr.z * 0.5f; py2[k] = pr.y + pr.w * 0.5f;
    pa[k] = (px2[k] - px1[k]) * (py2[k] - py1[k]);
    bov[k] = -1.f; bidx[k] = 0;
  }

  #pragma unroll 4
  for (int o = 0; o < O_; ++o) {
    const float x1 = tsh[o][0], y1 = tsh[o][1], x2 = tsh[o][2], y2 = tsh[o][3];
    const float ta = tsh[o][4];
    float tiou = 0.f;
    unsigned tinv = pinv[0];  // iou==0 contribution: smallest own p
    #pragma unroll
    for (int k = 0; k < KC_; ++k) {
      float iw = fmaxf(fminf(x2, px2[k]) - fmaxf(x1, px1[k]), 0.f);
      float ih = fmaxf(fminf(y2, py2[k]) - fmaxf(y1, py1[k]), 0.f);
      float inter = iw * ih;
      float iou = inter * frcp(ta + pa[k] - inter);
      if (iou > bov[k]) { bov[k] = iou; bidx[k] = o; }  // first occurrence (o asc)
      if (iou > tiou)   { tiou = iou; tinv = pinv[k]; } // first occurrence (p asc)
    }
    // 16-lane row max-reduce (fused DPP), then min-p among max lanes
    float m = tiou;
    m = dpp_fmax<0x128>(m);
    m = dpp_fmax<0x124>(m);
    m = dpp_fmax<0x122>(m);
    m = dpp_fmax<0x121>(m);
    unsigned cand = (tiou == m) ? tinv : 0u;
    cand = dpp_umax<0x128>(cand);
    cand = dpp_umax<0x124>(cand);
    cand = dpp_umax<0x122>(cand);
    cand = dpp_umax<0x121>(cand);
    if ((lane & 15) == 0)
      kq[o][wid * 4 + (lane >> 4)] =
          ((unsigned long long)__float_as_uint(m) << 32) | (unsigned long long)cand;
  }

  // ---- losses with UNFORCED (bov,bidx); k_fix corrects forced priors ----
  float vx = 0.f, vy = 0.f, vz = 0.f, vw = 0.f;
  #pragma unroll
  for (int k = 0; k < KC_; ++k) {
    const unsigned p = 0xFFFFFFFFu - pinv[k];
    const size_t bp = (size_t)b * P_ + p;
    const float ov = bov[k];
    const int idx = bidx[k];
    const bool pos = !(ov < THRESH_);
    const bool pos1 = pos && (tlbl[idx] > 0.f);
    float2 cf = reinterpret_cast<const float2*>(conf_data)[bp];
    vy += focal_term(cf, pos);
    if (pos) {
      float4 pr = reinterpret_cast<const float4*>(priors)[p];
      float4 loc = reinterpret_cast<const float4*>(loc_data)[bp];
      vx += giou_term(pr, loc, tsh[idx][0], tsh[idx][1], tsh[idx][2], tsh[idx][3]);
      if (pos1) {
        vw += 1.f;
        vz += landm_term(pr, landm_data + bp * 10, &tlm[idx][0]);
      }
    }
  }

  __syncthreads();
  // phase B: 32 threads reduce 16 row-partials each, one global atomic per o
  if (tid < O_) {
    unsigned long long best = kq[tid][0];
    #pragma unroll
    for (int s = 1; s < 16; ++s) {
      unsigned long long v = kq[tid][s];
      if (v > best) best = v;
    }
    atomicMax(&ws->gkey[(size_t)b * O_ + tid], best);
  }

  // block reduce -> one float4 partial per block, no atomics
  #pragma unroll
  for (int i = 32; i > 0; i >>= 1) {
    vx += __shfl_xor(vx, i);
    vy += __shfl_xor(vy, i);
    vz += __shfl_xor(vz, i);
    vw += __shfl_xor(vw, i);
  }
  if (lane == 0) wsum[wid] = make_float4(vx, vy, vz, vw);
  __syncthreads();
  if (tid == 0) {
    float sx = 0.f, sy = 0.f, sz = 0.f, sw = 0.f;
    #pragma unroll
    for (int w = 0; w < 4; ++w) {
      sx += wsum[w].x; sy += wsum[w].y; sz += wsum[w].z; sw += wsum[w].w;
    }
    ws->part[(size_t)blockIdx.y * GX_ + blockIdx.x] = make_float4(sx, sy, sz, sw);
  }
}

// ------- kernel 2: forced-match correction (32 blocks × 1 wave) -------------
__global__ __launch_bounds__(64) void k_fix(const float* __restrict__ loc_data,
                                            const float* __restrict__ conf_data,
                                            const float* __restrict__ landm_data,
                                            const float* __restrict__ priors,
                                            const float* __restrict__ targets,
                                            WSHdr* __restrict__ ws) {
  __shared__ float tsh[O_][5];
  __shared__ float tlbl[O_];
  __shared__ float tlm[O_][10];
  const int b = blockIdx.x;
  const int tid = threadIdx.x;
  if (tid < O_) {
    const float* trow = targets + ((size_t)b * O_ + tid) * 15;
    float x1 = trow[0], y1 = trow[1], x2 = trow[2], y2 = trow[3];
    tsh[tid][0] = x1; tsh[tid][1] = y1; tsh[tid][2] = x2; tsh[tid][3] = y2;
    tsh[tid][4] = (x2 - x1) * (y2 - y1);
    #pragma unroll
    for (int k = 0; k < 10; ++k) tlm[tid][k] = trow[4 + k];
    tlbl[tid] = trow[14];
  }
  __syncthreads();

  unsigned fp = 0xFFFFFFFFu;
  if (tid < O_)
    fp = 0xFFFFFFFFu - (unsigned)(ws->gkey[(size_t)b * O_ + tid] & 0xFFFFFFFFull);
  bool alive = tid < O_;
  // last-j-wins dedupe: j=tid survives iff no higher j maps to the same prior
  for (int j2 = 0; j2 < O_; ++j2) {
    unsigned f2 = __shfl(fp, j2, 64);
    if (j2 > tid && f2 == fp) alive = false;
  }

  float dll = 0.f, dlc = 0.f, dllm = 0.f, dn1 = 0.f;
  if (alive) {
    const int p = (int)fp;
    const size_t bp = (size_t)b * P_ + p;
    float4 pr = reinterpret_cast<const float4*>(priors)[p];
    // recompute unforced best exactly as k_fused did
    float px1 = pr.x - pr.z * 0.5f, py1 = pr.y - pr.w * 0.5f;
    float px2 = pr.x + pr.z * 0.5f, py2 = pr.y + pr.w * 0.5f;
    float pa = (px2 - px1) * (py2 - py1);
    float bov = -1.f;
    int bidx = 0;
    for (int o = 0; o < O_; ++o) {
      const float x1 = tsh[o][0], y1 = tsh[o][1], x2 = tsh[o][2], y2 = tsh[o][3];
      const float ta = tsh[o][4];
      float iw = fmaxf(fminf(x2, px2) - fmaxf(x1, px1), 0.f);
      float ih = fmaxf(fminf(y2, py2) - fmaxf(y1, py1), 0.f);
      float inter = iw * ih;
      float iou = inter * frcp(ta + pa - inter);
      if (iou > bov) { bov = iou; bidx = o; }
    }
    float2 cf = reinterpret_cast<const float2*>(conf_data)[bp];
    float4 loc = reinterpret_cast<const float4*>(loc_data)[bp];
    const float* lmrow = landm_data + bp * 10;
    // old (unforced) contribution — must mirror k_fused exactly
    {
      const bool pos = !(bov < THRESH_);
      const bool pos1 = pos && (tlbl[bidx] > 0.f);
      dlc -= focal_term(cf, pos);
      if (pos) {
        dll -= giou_term(pr, loc, tsh[bidx][0], tsh[bidx][1], tsh[bidx][2], tsh[bidx][3]);
        if (pos1) {
          dn1 -= 1.f;
          dllm -= landm_term(pr, lmrow, &tlm[bidx][0]);
        }
      }
    }
    // new (forced) contribution: ov=2 -> pos, idx = tid
    {
      const int idx = tid;
      const bool pos1 = tlbl[idx] > 0.f;
      dlc += focal_term(cf, true);
      dll += giou_term(pr, loc, tsh[idx][0], tsh[idx][1], tsh[idx][2], tsh[idx][3]);
      if (pos1) {
        dn1 += 1.f;
        dllm += landm_term(pr, lmrow, &tlm[idx][0]);
      }
    }
  }
  #pragma unroll
  for (int i = 32; i > 0; i >>= 1) {
    dll += __shfl_xor(dll, i);
    dlc += __shfl_xor(dlc, i);
    dllm += __shfl_xor(dllm, i);
    dn1 += __shfl_xor(dn1, i);
  }
  if (tid == 0) {
    ws->corr[b][0] = (double)dll;
    ws->corr[b][1] = (double)dlc;
    ws->corr[b][2] = (double)dllm;
    ws->corr[b][3] = (double)dn1;
  }
}

// ------- kernel 3: final reduction ------------------------------------------
__global__ __launch_bounds__(256) void k_final(const WSHdr* __restrict__ ws,
                                               float* __restrict__ out) {
  __shared__ double sh[4][4];
  const int tid = threadIdx.x;
  double sx = 0.0, sy = 0.0, sz = 0.0, sw = 0.0;
  for (int i = tid; i < GX_ * B_; i += 256) {
    float4 v = ws->part[i];
    sx += v.x; sy += v.y; sz += v.z; sw += v.w;
  }
  if (tid < B_) {
    sx += ws->corr[tid][0];
    sy += ws->corr[tid][1];
    sz += ws->corr[tid][2];
    sw += ws->corr[tid][3];
  }
  #pragma unroll
  for (int i = 32; i > 0; i >>= 1) {
    sx += __shfl_xor(sx, i);
    sy += __shfl_xor(sy, i);
    sz += __shfl_xor(sz, i);
    sw += __shfl_xor(sw, i);
  }
  const int wave = tid >> 6, lane = tid & 63;
  if (lane == 0) { sh[wave][0] = sx; sh[wave][1] = sy; sh[wave][2] = sz; sh[wave][3] = sw; }
  __syncthreads();
  if (tid == 0) {
    double ax = 0, ay = 0, az = 0, aw = 0;
    #pragma unroll
    for (int w = 0; w < 4; ++w) { ax += sh[w][0]; ay += sh[w][1]; az += sh[w][2]; aw += sh[w][3]; }
    double n1 = aw < 1.0 ? 1.0 : aw;
    out[0] = (float)(2.0 * ax / n1);  // LOC_W
    out[1] = (float)(ay / n1);
    out[2] = (float)(az / n1);        // LANDM_W
  }
}

extern "C" void kernel_launch(void* const* d_in, const int* in_sizes, int n_in,
                              void* d_out, int out_size, void* d_ws, size_t ws_size,
                              hipStream_t stream) {
  (void)in_sizes; (void)n_in; (void)out_size; (void)ws_size;
  const float* loc     = (const float*)d_in[0];
  const float* conf    = (const float*)d_in[1];
  const float* landm   = (const float*)d_in[2];
  const float* priors  = (const float*)d_in[3];
  const float* targets = (const float*)d_in[4];
  WSHdr* ws = (WSHdr*)d_ws;
  float* out = (float*)d_out;

  hipLaunchKernelGGL(init_ws, dim3(4), dim3(256), 0, stream, ws);
  hipLaunchKernelGGL(k_fused, dim3(GX_, B_), dim3(256), 0, stream,
                     loc, conf, landm, priors, targets, ws);
  hipLaunchKernelGGL(k_fix, dim3(B_), dim3(64), 0, stream,
                     loc, conf, landm, priors, targets, ws);
  hipLaunchKernelGGL(k_final, dim3(1), dim3(256), 0, stream, ws, out);
}

// Round 8
// 70.717 us; speedup vs baseline: 2.3616x; 1.0347x over previous
//
#include <hip/hip_runtime.h>
#include <cstdint>

#define B_ 32
#define P_ 65536
#define O_ 32
#define GX_ 64            // grid.x; each block handles KC_ chunks of 256 priors
#define KC_ 4             // (P_/256)/GX_
#define THRESH_ 0.35f
#define VAR0 0.1f
#define VAR1 0.2f
#define EPS_ 1e-7f
#define ALPHA_ 0.25f

struct WSHdr {
  unsigned long long gkey[B_ * O_];  // per (b,o): packed (trunc_iou_bits<<32)|(~p)
  float4 part[GX_ * B_];             // per-block partials (ll, lc, llm, n1)
  double corr[B_][4];                // per-batch forced-match corrections
};

__device__ __forceinline__ float frcp(float x) { return __builtin_amdgcn_rcpf(x); }

template <int CTRL>
__device__ __forceinline__ unsigned dpp_umax(unsigned v) {
  unsigned u = (unsigned)__builtin_amdgcn_update_dpp(0, (int)v, CTRL, 0xF, 0xF, true);
  return u > v ? u : v;
}

// ---- shared loss math (used by k_fused AND k_fix: identical expressions) ----
__device__ __forceinline__ float focal_term(float2 cf, bool pos) {
  float mx = fmaxf(cf.x, cf.y);
  float lse = mx + __logf(1.f + __expf(-fabsf(cf.x - cf.y)));
  float logpt = (pos ? cf.y : cf.x) - lse;
  float pt = __expf(logpt);
  float om = 1.f - pt;
  return -ALPHA_ * om * sqrtf(om) * logpt;  // alpha*(1-pt)^1.5*(-logpt)
}

__device__ __forceinline__ float giou_term(float4 pr, float4 loc,
                                           float b2x1, float b2y1,
                                           float b2x2, float b2y2) {
  float dx = pr.x + loc.x * VAR0 * pr.z;
  float dy = pr.y + loc.y * VAR0 * pr.w;
  float dw = pr.z * __expf(loc.z * VAR1);
  float dh = pr.w * __expf(loc.w * VAR1);
  float b1x1 = dx - dw * 0.5f, b1y1 = dy - dh * 0.5f;
  float b1x2 = dx + dw * 0.5f, b1y2 = dy + dh * 0.5f;
  float a1 = (b1x2 - b1x1) * (b1y2 - b1y1);
  float a2 = (b2x2 - b2x1) * (b2y2 - b2y1);
  float iw = fmaxf(fminf(b1x2, b2x2) - fmaxf(b1x1, b2x1), 0.f);
  float ih = fmaxf(fminf(b1y2, b2y2) - fmaxf(b1y1, b2y1), 0.f);
  float inter = iw * ih;
  float uni = a1 + a2 - inter;
  float iou = inter * frcp(uni + EPS_);
  float ew = fmaxf(b1x2, b2x2) - fminf(b1x1, b2x1);
  float eh = fmaxf(b1y2, b2y2) - fminf(b1y1, b2y1);
  float enc = ew * eh;
  float g = iou - (enc - uni) * frcp(enc + EPS_);
  return 1.f - g;
}

__device__ __forceinline__ float landm_term(float4 pr,
                                            const float* __restrict__ lmrow,
                                            const float* __restrict__ tlm_row) {
  float rw = frcp(VAR0 * pr.z);
  float rh = frcp(VAR0 * pr.w);
  float llm = 0.f;
  #pragma unroll
  for (int q = 0; q < 5; ++q) {
    float2 d = *reinterpret_cast<const float2*>(lmrow + q * 2);
    float ex = d.x - (tlm_row[2 * q] - pr.x) * rw;
    float ey = d.y - (tlm_row[2 * q + 1] - pr.y) * rh;
    float ax = fabsf(ex), ay = fabsf(ey);
    llm += (ax < 1.f) ? 0.5f * ex * ex : ax - 0.5f;
    llm += (ay < 1.f) ? 0.5f * ey * ey : ay - 0.5f;
  }
  return llm;
}

__global__ void init_ws(WSHdr* ws) {
  int t = blockIdx.x * blockDim.x + threadIdx.x;
  if (t < B_ * O_) ws->gkey[t] = 0ull;
}

// ------- kernel 1: fused match + unforced losses ----------------------------
__global__ __launch_bounds__(256) void k_fused(const float* __restrict__ loc_data,
                                               const float* __restrict__ conf_data,
                                               const float* __restrict__ landm_data,
                                               const float* __restrict__ priors,
                                               const float* __restrict__ targets,
                                               WSHdr* __restrict__ ws) {
  __shared__ float tsh[O_][4];                  // x1,y1,x2,y2 (loss section only)
  __shared__ float tlbl[O_];
  __shared__ float tlm[O_][10];
  __shared__ unsigned long long kq[O_][17];     // 16 row-partials + pad
  __shared__ float4 wsum[4];
  const int b = blockIdx.y;
  const int tid = threadIdx.x;
  const int lane = tid & 63, wid = tid >> 6;
  if (tid < O_) {
    const float* trow = targets + ((size_t)b * O_ + tid) * 15;
    tsh[tid][0] = trow[0]; tsh[tid][1] = trow[1];
    tsh[tid][2] = trow[2]; tsh[tid][3] = trow[3];
    #pragma unroll
    for (int k = 0; k < 10; ++k) tlm[tid][k] = trow[4 + k];
    tlbl[tid] = trow[14];
  }
  __syncthreads();

  // this thread's KC_ priors (corners), in registers
  float px1[KC_], py1[KC_], px2[KC_], py2[KC_], pa[KC_], bov[KC_];
  int bidx[KC_];
  #pragma unroll
  for (int k = 0; k < KC_; ++k) {
    unsigned p = (unsigned)((blockIdx.x + k * GX_) * 256 + tid);
    float4 pr = reinterpret_cast<const float4*>(priors)[p];
    px1[k] = pr.x - pr.z * 0.5f; py1[k] = pr.y - pr.w * 0.5f;
    px2[k] = pr.x + pr.z * 0.5f; py2[k] = pr.y + pr.w * 0.5f;
    pa[k] = (px2[k] - px1[k]) * (py2[k] - py1[k]);
    bov[k] = -1.f; bidx[k] = 0;
  }
  // per-thread packed low bits: ((3-k)<<4) | (15-row_lane)
  const unsigned rinv = 15u - (unsigned)(lane & 15);
  unsigned low6[KC_];
  #pragma unroll
  for (int k = 0; k < KC_; ++k) low6[k] = ((unsigned)(3 - k) << 4) | rinv;

  // truth coords via wave-uniform SCALAR loads (no LDS in hot loop)
  const float* __restrict__ tb = targets + (size_t)b * O_ * 15;

  #pragma unroll 4
  for (int o = 0; o < O_; ++o) {
    const float x1 = tb[o * 15 + 0], y1 = tb[o * 15 + 1];
    const float x2 = tb[o * 15 + 2], y2 = tb[o * 15 + 3];
    const float ta = (x2 - x1) * (y2 - y1);
    unsigned best = 0u;
    #pragma unroll
    for (int k = 0; k < KC_; ++k) {
      float iw = fmaxf(fminf(x2, px2[k]) - fmaxf(x1, px1[k]), 0.f);
      float ih = fmaxf(fminf(y2, py2[k]) - fmaxf(y1, py1[k]), 0.f);
      float inter = iw * ih;
      float iou = inter * frcp(ta + pa[k] - inter);
      if (iou > bov[k]) { bov[k] = iou; bidx[k] = o; }  // first occurrence (o asc)
      unsigned pk = (__float_as_uint(iou) & 0xFFFFFFC0u) | low6[k];
      best = pk > best ? pk : best;
    }
    // 16-lane row max-reduce: single 4-deep dpp_umax chain
    best = dpp_umax<0x128>(best);  // row_ror:8
    best = dpp_umax<0x124>(best);  // row_ror:4
    best = dpp_umax<0x122>(best);  // row_ror:2
    best = dpp_umax<0x121>(best);  // row_ror:1
    if ((lane & 15) == 0) {
      unsigned kw = 3u - ((best >> 4) & 3u);
      unsigned rw = 15u - (best & 15u);
      unsigned pw = (unsigned)((blockIdx.x + kw * GX_) * 256) + (unsigned)tid + rw;
      kq[o][wid * 4 + (lane >> 4)] =
          ((unsigned long long)(best & 0xFFFFFFC0u) << 32) |
          (unsigned long long)(0xFFFFFFFFu - pw);
    }
  }

  // ---- losses with UNFORCED (bov,bidx); k_fix corrects forced priors ----
  float vx = 0.f, vy = 0.f, vz = 0.f, vw = 0.f;
  #pragma unroll
  for (int k = 0; k < KC_; ++k) {
    const unsigned p = (unsigned)((blockIdx.x + k * GX_) * 256 + tid);
    const size_t bp = (size_t)b * P_ + p;
    const float ov = bov[k];
    const int idx = bidx[k];
    const bool pos = !(ov < THRESH_);
    const bool pos1 = pos && (tlbl[idx] > 0.f);
    float2 cf = reinterpret_cast<const float2*>(conf_data)[bp];
    vy += focal_term(cf, pos);
    if (pos) {
      float4 pr = reinterpret_cast<const float4*>(priors)[p];
      float4 loc = reinterpret_cast<const float4*>(loc_data)[bp];
      vx += giou_term(pr, loc, tsh[idx][0], tsh[idx][1], tsh[idx][2], tsh[idx][3]);
      if (pos1) {
        vw += 1.f;
        vz += landm_term(pr, landm_data + bp * 10, &tlm[idx][0]);
      }
    }
  }

  __syncthreads();
  // phase B: 32 threads reduce 16 row-partials each, one global atomic per o
  if (tid < O_) {
    unsigned long long best = kq[tid][0];
    #pragma unroll
    for (int s = 1; s < 16; ++s) {
      unsigned long long v = kq[tid][s];
      if (v > best) best = v;
    }
    atomicMax(&ws->gkey[(size_t)b * O_ + tid], best);
  }

  // block reduce -> one float4 partial per block, no atomics
  #pragma unroll
  for (int i = 32; i > 0; i >>= 1) {
    vx += __shfl_xor(vx, i);
    vy += __shfl_xor(vy, i);
    vz += __shfl_xor(vz, i);
    vw += __shfl_xor(vw, i);
  }
  if (lane == 0) wsum[wid] = make_float4(vx, vy, vz, vw);
  __syncthreads();
  if (tid == 0) {
    float sx = 0.f, sy = 0.f, sz = 0.f, sw = 0.f;
    #pragma unroll
    for (int w = 0; w < 4; ++w) {
      sx += wsum[w].x; sy += wsum[w].y; sz += wsum[w].z; sw += wsum[w].w;
    }
    ws->part[(size_t)blockIdx.y * GX_ + blockIdx.x] = make_float4(sx, sy, sz, sw);
  }
}

// ------- kernel 2: forced-match correction (32 blocks × 1 wave) -------------
__global__ __launch_bounds__(64) void k_fix(const float* __restrict__ loc_data,
                                            const float* __restrict__ conf_data,
                                            const float* __restrict__ landm_data,
                                            const float* __restrict__ priors,
                                            const float* __restrict__ targets,
                                            WSHdr* __restrict__ ws) {
  __shared__ float tsh[O_][5];
  __shared__ float tlbl[O_];
  __shared__ float tlm[O_][10];
  const int b = blockIdx.x;
  const int tid = threadIdx.x;
  if (tid < O_) {
    const float* trow = targets + ((size_t)b * O_ + tid) * 15;
    float x1 = trow[0], y1 = trow[1], x2 = trow[2], y2 = trow[3];
    tsh[tid][0] = x1; tsh[tid][1] = y1; tsh[tid][2] = x2; tsh[tid][3] = y2;
    tsh[tid][4] = (x2 - x1) * (y2 - y1);
    #pragma unroll
    for (int k = 0; k < 10; ++k) tlm[tid][k] = trow[4 + k];
    tlbl[tid] = trow[14];
  }
  __syncthreads();

  unsigned fp = 0xFFFFFFFFu;
  if (tid < O_)
    fp = 0xFFFFFFFFu - (unsigned)(ws->gkey[(size_t)b * O_ + tid] & 0xFFFFFFFFull);
  bool alive = tid < O_;
  // last-j-wins dedupe: j=tid survives iff no higher j maps to the same prior
  for (int j2 = 0; j2 < O_; ++j2) {
    unsigned f2 = __shfl(fp, j2, 64);
    if (j2 > tid && f2 == fp) alive = false;
  }

  float dll = 0.f, dlc = 0.f, dllm = 0.f, dn1 = 0.f;
  if (alive) {
    const int p = (int)fp;
    const size_t bp = (size_t)b * P_ + p;
    float4 pr = reinterpret_cast<const float4*>(priors)[p];
    // recompute unforced best exactly as k_fused did (exact float iou, o asc)
    float px1 = pr.x - pr.z * 0.5f, py1 = pr.y - pr.w * 0.5f;
    float px2 = pr.x + pr.z * 0.5f, py2 = pr.y + pr.w * 0.5f;
    float pa = (px2 - px1) * (py2 - py1);
    float bov = -1.f;
    int bidx = 0;
    for (int o = 0; o < O_; ++o) {
      const float x1 = tsh[o][0], y1 = tsh[o][1], x2 = tsh[o][2], y2 = tsh[o][3];
      const float ta = tsh[o][4];
      float iw = fmaxf(fminf(x2, px2) - fmaxf(x1, px1), 0.f);
      float ih = fmaxf(fminf(y2, py2) - fmaxf(y1, py1), 0.f);
      float inter = iw * ih;
      float iou = inter * frcp(ta + pa - inter);
      if (iou > bov) { bov = iou; bidx = o; }
    }
    float2 cf = reinterpret_cast<const float2*>(conf_data)[bp];
    float4 loc = reinterpret_cast<const float4*>(loc_data)[bp];
    const float* lmrow = landm_data + bp * 10;
    // old (unforced) contribution — mirrors k_fused exactly
    {
      const bool pos = !(bov < THRESH_);
      const bool pos1 = pos && (tlbl[bidx] > 0.f);
      dlc -= focal_term(cf, pos);
      if (pos) {
        dll -= giou_term(pr, loc, tsh[bidx][0], tsh[bidx][1], tsh[bidx][2], tsh[bidx][3]);
        if (pos1) {
          dn1 -= 1.f;
          dllm -= landm_term(pr, lmrow, &tlm[bidx][0]);
        }
      }
    }
    // new (forced) contribution: ov=2 -> pos, idx = tid
    {
      const int idx = tid;
      const bool pos1 = tlbl[idx] > 0.f;
      dlc += focal_term(cf, true);
      dll += giou_term(pr, loc, tsh[idx][0], tsh[idx][1], tsh[idx][2], tsh[idx][3]);
      if (pos1) {
        dn1 += 1.f;
        dllm += landm_term(pr, lmrow, &tlm[idx][0]);
      }
    }
  }
  #pragma unroll
  for (int i = 32; i > 0; i >>= 1) {
    dll += __shfl_xor(dll, i);
    dlc += __shfl_xor(dlc, i);
    dllm += __shfl_xor(dllm, i);
    dn1 += __shfl_xor(dn1, i);
  }
  if (tid == 0) {
    ws->corr[b][0] = (double)dll;
    ws->corr[b][1] = (double)dlc;
    ws->corr[b][2] = (double)dllm;
    ws->corr[b][3] = (double)dn1;
  }
}

// ------- kernel 3: final reduction ------------------------------------------
__global__ __launch_bounds__(256) void k_final(const WSHdr* __restrict__ ws,
                                               float* __restrict__ out) {
  __shared__ double sh[4][4];
  const int tid = threadIdx.x;
  double sx = 0.0, sy = 0.0, sz = 0.0, sw = 0.0;
  for (int i = tid; i < GX_ * B_; i += 256) {
    float4 v = ws->part[i];
    sx += v.x; sy += v.y; sz += v.z; sw += v.w;
  }
  if (tid < B_) {
    sx += ws->corr[tid][0];
    sy += ws->corr[tid][1];
    sz += ws->corr[tid][2];
    sw += ws->corr[tid][3];
  }
  #pragma unroll
  for (int i = 32; i > 0; i >>= 1) {
    sx += __shfl_xor(sx, i);
    sy += __shfl_xor(sy, i);
    sz += __shfl_xor(sz, i);
    sw += __shfl_xor(sw, i);
  }
  const int wave = tid >> 6, lane = tid & 63;
  if (lane == 0) { sh[wave][0] = sx; sh[wave][1] = sy; sh[wave][2] = sz; sh[wave][3] = sw; }
  __syncthreads();
  if (tid == 0) {
    double ax = 0, ay = 0, az = 0, aw = 0;
    #pragma unroll
    for (int w = 0; w < 4; ++w) { ax += sh[w][0]; ay += sh[w][1]; az += sh[w][2]; aw += sh[w][3]; }
    double n1 = aw < 1.0 ? 1.0 : aw;
    out[0] = (float)(2.0 * ax / n1);  // LOC_W
    out[1] = (float)(ay / n1);
    out[2] = (float)(az / n1);        // LANDM_W
  }
}

extern "C" void kernel_launch(void* const* d_in, const int* in_sizes, int n_in,
                              void* d_out, int out_size, void* d_ws, size_t ws_size,
                              hipStream_t stream) {
  (void)in_sizes; (void)n_in; (void)out_size; (void)ws_size;
  const float* loc     = (const float*)d_in[0];
  const float* conf    = (const float*)d_in[1];
  const float* landm   = (const float*)d_in[2];
  const float* priors  = (const float*)d_in[3];
  const float* targets = (const float*)d_in[4];
  WSHdr* ws = (WSHdr*)d_ws;
  float* out = (float*)d_out;

  hipLaunchKernelGGL(init_ws, dim3(4), dim3(256), 0, stream, ws);
  hipLaunchKernelGGL(k_fused, dim3(GX_, B_), dim3(256), 0, stream,
                     loc, conf, landm, priors, targets, ws);
  hipLaunchKernelGGL(k_fix, dim3(B_), dim3(64), 0, stream,
                     loc, conf, landm, priors, targets, ws);
  hipLaunchKernelGGL(k_final, dim3(1), dim3(256), 0, stream, ws, out);
}